// Round 3
// baseline (73.863 us; speedup 1.0000x reference)
//
#include <hip/hip_runtime.h>
#include <hip/hip_bf16.h>

#define NPTS 8192
#define NB   4
#define BLK  256
#define QPT  4
#define QPB  (QPT * BLK)          // 1024 queries per block
#define NQC_MAX (NPTS / QPB)      // 8 query chunks (capacity)
#define NSL  16                   // search slices
#define SLICE_MAX ((NPTS + NSL - 1) / NSL)   // 512 -> 8 KiB LDS
#define CAP  NPTS
#define THR  3.33f
#define NCB  (NPTS / BLK)                    // 32 compact blocks per (b,side)
#define FIN_BLOCKS (NCB * 2 * NB)            // 256 finalize blocks

// workspace layout (bytes):
//   [0,32)    counts (8 u32)
//   [32,64)   sums   (8 f32)
//   [64,96)   cnts   (8 f32)
//   [96,100)  done   (1 u32)
//   [128, 128+8*CAP*4)               best (u32)
//   [128+8*CAP*4, +8*CAP*16)         pts  (float4)
#define OFF_SUMS 32
#define OFF_CNTS 64
#define OFF_DONE 96
#define OFF_BEST 128
#define OFF_PTS  (128 + 8 * CAP * 4)

__device__ __forceinline__ unsigned enc_f(float f) {
    unsigned u = __float_as_uint(f);
    return (u & 0x80000000u) ? ~u : (u | 0x80000000u);
}
__device__ __forceinline__ float dec_f(unsigned u) {
    return (u & 0x80000000u) ? __uint_as_float(u & 0x7FFFFFFFu)
                             : __uint_as_float(~u);
}

// Zero the 128-byte control region (counts/sums/cnts/done).
__global__ void init_kernel(unsigned* __restrict__ ws) {
    if (threadIdx.x < 32) ws[threadIdx.x] = 0;
}

// ---------------------------------------------------------------------------
// Compact valid points per (batch, side); also zeroes `best` (one word per
// thread: grid has exactly 8*CAP threads). side 0 = warped src, 1 = dst.
// Encoded as (2x, 2y, 2z, -(x^2+y^2+z^2)); append order irrelevant.
// ---------------------------------------------------------------------------
__global__ __launch_bounds__(BLK) void compact_kernel(
    const float* __restrict__ Ps, const float* __restrict__ Pd,
    const float* __restrict__ F,  const int* __restrict__ Ms,
    const int* __restrict__ Md,   unsigned* __restrict__ counts,
    float4* __restrict__ pts,     unsigned* __restrict__ best)
{
    const int b = blockIdx.z, side = blockIdx.y;
    const int i = blockIdx.x * BLK + threadIdx.x;
    const int g = b * NPTS + i;

    // zero my best slot (runs before knn in-stream; no intra-kernel ordering needed)
    best[((size_t)(b * 2 + side) * NCB + blockIdx.x) * BLK + threadIdx.x] = 0u;

    float x, y, z; int v;
    if (side == 0) {
        x = Ps[3 * g + 0] + F[3 * g + 0];
        y = Ps[3 * g + 1] + F[3 * g + 1];
        z = Ps[3 * g + 2] + F[3 * g + 2];
        v = Ms[g];
    } else {
        x = Pd[3 * g + 0]; y = Pd[3 * g + 1]; z = Pd[3 * g + 2];
        v = Md[g];
    }
    if (v > 0) {
        unsigned pos = atomicAdd(&counts[b * 2 + side], 1u);
        pts[(size_t)(b * 2 + side) * CAP + pos] =
            make_float4(2.f * x, 2.f * y, 2.f * z, -(x * x + y * y + z * z));
    }
}

// ---------------------------------------------------------------------------
// For each (b,dir): queries side=dir, search side=1-dir.
// max over search slice of t = 2*q.s - |s|^2 ; combine via atomicMax(enc).
// ---------------------------------------------------------------------------
__global__ __launch_bounds__(BLK) void knn_kernel(
    const unsigned* __restrict__ counts, const float4* __restrict__ pts,
    unsigned* __restrict__ best)
{
    const int b = blockIdx.z, d = blockIdx.y;
    const int qc = blockIdx.x / NSL, sl = blockIdx.x % NSL;
    const int qi = b * 2 + d;
    const int si = b * 2 + (1 - d);
    const int nq = (int)counts[qi];
    const int ns = (int)counts[si];
    if (qc * QPB >= nq) return;                  // uniform exit
    const int slice = (ns + NSL - 1) / NSL;
    const int start = sl * slice;
    int len = ns - start; if (len > slice) len = slice;
    if (len <= 0) return;                        // uniform exit

    __shared__ float4 sp[SLICE_MAX];
    const float4* __restrict__ sarr = pts + (size_t)si * CAP + start;
    for (int i = threadIdx.x; i < len; i += BLK) sp[i] = sarr[i];
    __syncthreads();

    const float4* __restrict__ qarr = pts + (size_t)qi * CAP;
    float qx[QPT], qy[QPT], qz[QPT], bt[QPT];
    int qn_[QPT]; bool qv[QPT];
#pragma unroll
    for (int k = 0; k < QPT; ++k) {
        const int q = qc * QPB + k * BLK + threadIdx.x;
        qn_[k] = q; qv[k] = (q < nq);
        float4 p = qarr[qv[k] ? q : 0];
        qx[k] = 0.5f * p.x; qy[k] = 0.5f * p.y; qz[k] = 0.5f * p.z;
        bt[k] = -1e30f;
    }

#pragma unroll 4
    for (int j = 0; j < len; ++j) {
        const float4 s = sp[j];                  // wave-uniform -> LDS broadcast
#pragma unroll
        for (int k = 0; k < QPT; ++k) {
            float t = fmaf(qx[k], s.x, s.w);
            t = fmaf(qy[k], s.y, t);
            t = fmaf(qz[k], s.z, t);
            bt[k] = fmaxf(bt[k], t);
        }
    }

#pragma unroll
    for (int k = 0; k < QPT; ++k)
        if (qv[k]) atomicMax(&best[(size_t)qi * CAP + qn_[k]], enc_f(bt[k]));
}

// ---------------------------------------------------------------------------
// Decode best, d = |q|^2 - t (clamped), threshold, wave-reduce, atomicAdd.
// Last block (done-counter) computes the final scalar output.
// ---------------------------------------------------------------------------
__global__ __launch_bounds__(BLK) void finalize_kernel(
    const unsigned* __restrict__ counts, const float4* __restrict__ pts,
    const unsigned* __restrict__ best, float* __restrict__ sums,
    float* __restrict__ cnts, unsigned* __restrict__ done,
    float* __restrict__ out)
{
    const int b = blockIdx.z, d = blockIdx.y;
    const int qi = b * 2 + d;
    const int q = blockIdx.x * BLK + threadIdx.x;
    const int nq = (int)counts[qi];
    float s = 0.f, c = 0.f;
    if (q < nq) {
        const float4 p = pts[(size_t)qi * CAP + q];
        const float t = dec_f(best[(size_t)qi * CAP + q]);
        float dd = (-p.w) - t;
        dd = fmaxf(dd, 0.f);
        if (dd < THR) { s = dd; c = 1.f; }
    }
#pragma unroll
    for (int off = 32; off; off >>= 1) {
        s += __shfl_down(s, off);
        c += __shfl_down(c, off);
    }
    if ((threadIdx.x & 63) == 0) {
        atomicAdd(&sums[qi], s);
        atomicAdd(&cnts[qi], c);
    }
    __threadfence();          // make this block's atomics visible device-wide
    __syncthreads();          // all waves' atomics issued+drained before ticket
    if (threadIdx.x == 0) {
        unsigned r = __hip_atomic_fetch_add(done, 1u, __ATOMIC_ACQ_REL,
                                            __HIP_MEMORY_SCOPE_AGENT);
        if (r == FIN_BLOCKS - 1) {
            float a = 0.f;
#pragma unroll
            for (int i = 0; i < 2 * NB; ++i) {
                float ss = __hip_atomic_load(&sums[i], __ATOMIC_RELAXED,
                                             __HIP_MEMORY_SCOPE_AGENT);
                float cc = __hip_atomic_load(&cnts[i], __ATOMIC_RELAXED,
                                             __HIP_MEMORY_SCOPE_AGENT);
                a += ss / cc;
            }
            out[0] = a;
        }
    }
}

extern "C" void kernel_launch(void* const* d_in, const int* in_sizes, int n_in,
                              void* d_out, int out_size, void* d_ws, size_t ws_size,
                              hipStream_t stream)
{
    const float* Ps = (const float*)d_in[0];
    const float* Pd = (const float*)d_in[1];
    const float* F  = (const float*)d_in[2];
    const int* Ms = (const int*)d_in[4];
    const int* Md = (const int*)d_in[5];
    float* out = (float*)d_out;

    unsigned* counts = (unsigned*)d_ws;
    float* sums = (float*)((char*)d_ws + OFF_SUMS);
    float* cnts = (float*)((char*)d_ws + OFF_CNTS);
    unsigned* done = (unsigned*)((char*)d_ws + OFF_DONE);
    unsigned* best = (unsigned*)((char*)d_ws + OFF_BEST);
    float4* pts = (float4*)((char*)d_ws + OFF_PTS);

    init_kernel<<<1, 64, 0, stream>>>((unsigned*)d_ws);

    compact_kernel<<<dim3(NCB, 2, NB), BLK, 0, stream>>>(
        Ps, Pd, F, Ms, Md, counts, pts, best);

    knn_kernel<<<dim3(NQC_MAX * NSL, 2, NB), BLK, 0, stream>>>(counts, pts, best);

    finalize_kernel<<<dim3(NCB, 2, NB), BLK, 0, stream>>>(
        counts, pts, best, sums, cnts, done, out);
}

// Round 4
// 35.620 us; speedup vs baseline: 2.0737x; 2.0737x over previous
//
#include <hip/hip_runtime.h>
#include <hip/hip_bf16.h>

#define NPTS 8192
#define NB   4
#define BLK  256
#define NREG 32                    // regions per (b,side) = NPTS/BLK
#define QPT  4                     // query regions per knn block
#define NQC  (NREG / QPT)          // 8 query chunks
#define NSL  16                    // search slices; 2 regions per slice
#define SLICE_MAX 512              // 2*BLK -> 8 KiB LDS
#define CAP  NPTS
#define THR  3.33f

// workspace layout (bytes), everything written unconditionally each call:
//   [0, 1024)        bcnt  (8*NREG u32)   per-region valid counts
//   [4096, 5120)     psum  (8*NREG f32)   per-region partial sums
//   [8192, 9216)     pcnt  (8*NREG f32)   per-region partial counts
//   [16384, +256K)   best  (8*CAP u32)    zeroed by compact each call
//   [16384+256K, ..) pts   (8*CAP float4) compacted encoded points
#define OFF_PSUM 4096
#define OFF_PCNT 8192
#define OFF_BEST 16384
#define OFF_PTS  (16384 + 8 * CAP * 4)

__device__ __forceinline__ unsigned enc_f(float f) {
    unsigned u = __float_as_uint(f);
    return (u & 0x80000000u) ? ~u : (u | 0x80000000u);
}
__device__ __forceinline__ float dec_f(unsigned u) {
    return (u & 0x80000000u) ? __uint_as_float(u & 0x7FFFFFFFu)
                             : __uint_as_float(~u);
}

// ---------------------------------------------------------------------------
// Compact valid points into per-block regions (no pre-zeroed counters needed).
// side 0 = warped src (Ps+F, Ms), side 1 = dst (Pd, Md).
// Encoded as (2x, 2y, 2z, -(x^2+y^2+z^2)). Also zeroes this block's best slots.
// ---------------------------------------------------------------------------
__global__ __launch_bounds__(BLK) void compact_kernel(
    const float* __restrict__ Ps, const float* __restrict__ Pd,
    const float* __restrict__ F,  const int* __restrict__ Ms,
    const int* __restrict__ Md,   unsigned* __restrict__ bcnt,
    float4* __restrict__ pts,     unsigned* __restrict__ best)
{
    const int b = blockIdx.z, side = blockIdx.y, r = blockIdx.x;
    const int qi = b * 2 + side;
    const int tid = threadIdx.x;
    const int g = b * NPTS + r * BLK + tid;

    best[(size_t)qi * CAP + r * BLK + tid] = 0u;   // knn runs after -> safe

    float x, y, z; int v;
    if (side == 0) {
        x = Ps[3 * g + 0] + F[3 * g + 0];
        y = Ps[3 * g + 1] + F[3 * g + 1];
        z = Ps[3 * g + 2] + F[3 * g + 2];
        v = Ms[g];
    } else {
        x = Pd[3 * g + 0]; y = Pd[3 * g + 1]; z = Pd[3 * g + 2];
        v = Md[g];
    }
    const bool valid = v > 0;

    // block-local prefix: ballot within wave, wave counts via LDS
    const int lane = tid & 63, w = tid >> 6;
    unsigned long long m = __ballot(valid);
    const int my = __popcll(m & ((1ull << lane) - 1ull));
    __shared__ int wc[4];
    if (lane == 0) wc[w] = __popcll(m);
    __syncthreads();
    int off = 0;
#pragma unroll
    for (int i = 0; i < 4; ++i) if (i < w) off += wc[i];
    if (valid)
        pts[(size_t)qi * CAP + r * BLK + off + my] =
            make_float4(2.f * x, 2.f * y, 2.f * z, -(x * x + y * y + z * z));
    if (tid == 0)
        bcnt[qi * NREG + r] = (unsigned)(wc[0] + wc[1] + wc[2] + wc[3]);
}

// ---------------------------------------------------------------------------
// For (b,dir): queries side=dir, search side=1-dir. Each block: 4 query
// regions x 2 search regions. max of t = 2*q.s - |s|^2; combine atomicMax(enc).
// ---------------------------------------------------------------------------
__global__ __launch_bounds__(BLK) void knn_kernel(
    const unsigned* __restrict__ bcnt, const float4* __restrict__ pts,
    unsigned* __restrict__ best)
{
    const int b = blockIdx.z, d = blockIdx.y;
    const int qc = blockIdx.x / NSL, sl = blockIdx.x % NSL;
    const int qi = b * 2 + d;
    const int si = b * 2 + (1 - d);
    const int tid = threadIdx.x;

    const int r0 = 2 * sl, r1 = 2 * sl + 1;
    const int c0 = (int)bcnt[si * NREG + r0];
    const int c1 = (int)bcnt[si * NREG + r1];
    const int len = c0 + c1;

    __shared__ float4 sp[SLICE_MAX];
    const float4* __restrict__ s0 = pts + (size_t)si * CAP + r0 * BLK;
    const float4* __restrict__ s1 = pts + (size_t)si * CAP + r1 * BLK;
    if (tid < c0) sp[tid] = s0[tid];
    if (tid < c1) sp[c0 + tid] = s1[tid];
    __syncthreads();

    float qx[QPT], qy[QPT], qz[QPT], bt[QPT];
    bool qv[QPT]; int qr[QPT];
#pragma unroll
    for (int k = 0; k < QPT; ++k) {
        qr[k] = qc * QPT + k;
        qv[k] = tid < (int)bcnt[qi * NREG + qr[k]];
        const float4 p = pts[(size_t)qi * CAP + qr[k] * BLK + tid];
        qx[k] = 0.5f * p.x; qy[k] = 0.5f * p.y; qz[k] = 0.5f * p.z;
        bt[k] = -1e30f;
    }

#pragma unroll 4
    for (int j = 0; j < len; ++j) {
        const float4 s = sp[j];            // wave-uniform -> LDS broadcast
#pragma unroll
        for (int k = 0; k < QPT; ++k) {
            float t = fmaf(qx[k], s.x, s.w);
            t = fmaf(qy[k], s.y, t);
            t = fmaf(qz[k], s.z, t);
            bt[k] = fmaxf(bt[k], t);
        }
    }

#pragma unroll
    for (int k = 0; k < QPT; ++k)
        if (qv[k])
            atomicMax(&best[(size_t)qi * CAP + qr[k] * BLK + tid], enc_f(bt[k]));
}

// ---------------------------------------------------------------------------
// One block per (b,side,region): decode best, d = |q|^2 - t, threshold,
// reduce to per-region partials with plain stores (no init required).
// ---------------------------------------------------------------------------
__global__ __launch_bounds__(BLK) void finalize_kernel(
    const unsigned* __restrict__ bcnt, const float4* __restrict__ pts,
    const unsigned* __restrict__ best, float* __restrict__ psum,
    float* __restrict__ pcnt)
{
    const int b = blockIdx.z, side = blockIdx.y, r = blockIdx.x;
    const int qi = b * 2 + side;
    const int tid = threadIdx.x;
    float s = 0.f, c = 0.f;
    if (tid < (int)bcnt[qi * NREG + r]) {
        const float4 p = pts[(size_t)qi * CAP + r * BLK + tid];
        const float t = dec_f(best[(size_t)qi * CAP + r * BLK + tid]);
        float dd = fmaxf((-p.w) - t, 0.f);
        if (dd < THR) { s = dd; c = 1.f; }
    }
#pragma unroll
    for (int off = 32; off; off >>= 1) {
        s += __shfl_down(s, off);
        c += __shfl_down(c, off);
    }
    __shared__ float red[8];
    const int w = tid >> 6;
    if ((tid & 63) == 0) { red[w] = s; red[4 + w] = c; }
    __syncthreads();
    if (tid == 0) {
        psum[qi * NREG + r] = red[0] + red[1] + red[2] + red[3];
        pcnt[qi * NREG + r] = red[4] + red[5] + red[6] + red[7];
    }
}

// Sum 256 partials -> scalar. 1 block, 64 threads; lanes 0..7 own one qi each.
__global__ void reduce_out_kernel(const float* __restrict__ psum,
                                  const float* __restrict__ pcnt,
                                  float* __restrict__ out)
{
    const int tid = threadIdx.x;
    float a = 0.f;
    if (tid < 8) {
        float s = 0.f, c = 0.f;
        for (int r = 0; r < NREG; ++r) {
            s += psum[tid * NREG + r];
            c += pcnt[tid * NREG + r];
        }
        a = s / c;
    }
#pragma unroll
    for (int off = 4; off; off >>= 1) a += __shfl_down(a, off);
    if (tid == 0) out[0] = a;
}

extern "C" void kernel_launch(void* const* d_in, const int* in_sizes, int n_in,
                              void* d_out, int out_size, void* d_ws, size_t ws_size,
                              hipStream_t stream)
{
    const float* Ps = (const float*)d_in[0];   // points_src  [B,N,3]
    const float* Pd = (const float*)d_in[1];   // points_dst  [B,N,3]
    const float* F  = (const float*)d_in[2];   // flows_pred  [B,N,3]
    // d_in[3] = flows_gt (unused by reference)
    const int* Ms = (const int*)d_in[4];       // masks_src [B,N]
    const int* Md = (const int*)d_in[5];       // masks_dst [B,N]
    float* out = (float*)d_out;

    unsigned* bcnt = (unsigned*)d_ws;
    float* psum = (float*)((char*)d_ws + OFF_PSUM);
    float* pcnt = (float*)((char*)d_ws + OFF_PCNT);
    unsigned* best = (unsigned*)((char*)d_ws + OFF_BEST);
    float4* pts = (float4*)((char*)d_ws + OFF_PTS);

    compact_kernel<<<dim3(NREG, 2, NB), BLK, 0, stream>>>(
        Ps, Pd, F, Ms, Md, bcnt, pts, best);

    knn_kernel<<<dim3(NQC * NSL, 2, NB), BLK, 0, stream>>>(bcnt, pts, best);

    finalize_kernel<<<dim3(NREG, 2, NB), BLK, 0, stream>>>(
        bcnt, pts, best, psum, pcnt);

    reduce_out_kernel<<<1, 64, 0, stream>>>(psum, pcnt, out);
}

// Round 5
// 33.971 us; speedup vs baseline: 2.1743x; 1.0485x over previous
//
#include <hip/hip_runtime.h>
#include <hip/hip_bf16.h>

#define NPTS 8192
#define NB   4
#define BLK  256
#define NREG 32                    // regions per (b,side) = NPTS/BLK
#define QPT  4                     // dense queries per thread
#define QPB  (QPT * BLK)           // 1024 dense queries per block
#define NQC_MAX (NPTS / QPB)       // 8 chunks (worst case all valid)
#define NSL  32                    // search slices over dense ids
#define SMAX ((NPTS + NSL - 1) / NSL)   // 256 -> 4 KiB LDS
#define CAP  NPTS
#define THR  3.33f

// workspace (all regions rewritten every call; no init node needed):
//   [0, 1024)        bcnt  (8*NREG u32)  per-region valid counts
//   [4096, 5120)     psum  (8*NREG f32)  per-block partial sums
//   [8192, 9216)     pcnt  (8*NREG f32)  per-block partial counts
//   [16384, +256K)   best  (8*CAP u32)   zeroed by compact each call
//   [16384+256K, ..) pts   (8*CAP float4) region-packed encoded points
#define OFF_PSUM 4096
#define OFF_PCNT 8192
#define OFF_BEST 16384
#define OFF_PTS  (16384 + 8 * CAP * 4)

__device__ __forceinline__ unsigned enc_f(float f) {
    unsigned u = __float_as_uint(f);
    return (u & 0x80000000u) ? ~u : (u | 0x80000000u);
}
__device__ __forceinline__ float dec_f(unsigned u) {
    return (u & 0x80000000u) ? __uint_as_float(u & 0x7FFFFFFFu)
                             : __uint_as_float(~u);
}

// wave-0 inclusive shfl-scan of one side's 32 region counts -> P[0..32] in LDS
__device__ __forceinline__ void build_prefix(const unsigned* __restrict__ bcnt,
                                             int qi, int* P, int tid) {
    if (tid < 64) {
        const int lane = tid & 63;
        int v = (lane < NREG) ? (int)bcnt[qi * NREG + lane] : 0;
#pragma unroll
        for (int o = 1; o < NREG; o <<= 1) {
            int t = __shfl_up(v, o);
            if (lane >= o) v += t;
        }
        if (lane < NREG) P[lane + 1] = v;
        if (lane == 0) P[0] = 0;
    }
}

// branchless 5-step search: largest r in [0,32) with P[r] <= id
__device__ __forceinline__ int map_region(const int* P, int id) {
    int r = 0;
#pragma unroll
    for (int s = 16; s; s >>= 1)
        if (P[r + s] <= id) r += s;
    return r;
}

// ---------------------------------------------------------------------------
// Compact valid points into per-block regions; zero own best slots.
// side 0 = warped src (Ps+F, Ms), side 1 = dst (Pd, Md).
// Encoded as (2x, 2y, 2z, -(x^2+y^2+z^2)).
// ---------------------------------------------------------------------------
__global__ __launch_bounds__(BLK) void compact_kernel(
    const float* __restrict__ Ps, const float* __restrict__ Pd,
    const float* __restrict__ F,  const int* __restrict__ Ms,
    const int* __restrict__ Md,   unsigned* __restrict__ bcnt,
    float4* __restrict__ pts,     unsigned* __restrict__ best)
{
    const int b = blockIdx.z, side = blockIdx.y, r = blockIdx.x;
    const int qi = b * 2 + side;
    const int tid = threadIdx.x;
    const int g = b * NPTS + r * BLK + tid;

    best[(size_t)qi * CAP + r * BLK + tid] = 0u;   // knn runs after -> safe

    float x, y, z; int v;
    if (side == 0) {
        x = Ps[3 * g + 0] + F[3 * g + 0];
        y = Ps[3 * g + 1] + F[3 * g + 1];
        z = Ps[3 * g + 2] + F[3 * g + 2];
        v = Ms[g];
    } else {
        x = Pd[3 * g + 0]; y = Pd[3 * g + 1]; z = Pd[3 * g + 2];
        v = Md[g];
    }
    const bool valid = v > 0;

    const int lane = tid & 63, w = tid >> 6;
    unsigned long long m = __ballot(valid);
    const int my = __popcll(m & ((1ull << lane) - 1ull));
    __shared__ int wc[4];
    if (lane == 0) wc[w] = __popcll(m);
    __syncthreads();
    int off = 0;
#pragma unroll
    for (int i = 0; i < 4; ++i) if (i < w) off += wc[i];
    if (valid)
        pts[(size_t)qi * CAP + r * BLK + off + my] =
            make_float4(2.f * x, 2.f * y, 2.f * z, -(x * x + y * y + z * z));
    if (tid == 0)
        bcnt[qi * NREG + r] = (unsigned)(wc[0] + wc[1] + wc[2] + wc[3]);
}

// ---------------------------------------------------------------------------
// Dense knn: queries side=dir, search side=1-dir, both addressed by dense
// compact index via prefix map. max of t = 2*q.s - |s|^2; atomicMax(enc).
// ---------------------------------------------------------------------------
__global__ __launch_bounds__(BLK) void knn_kernel(
    const unsigned* __restrict__ bcnt, const float4* __restrict__ pts,
    unsigned* __restrict__ best)
{
    const int b = blockIdx.z, d = blockIdx.y;
    const int qc = blockIdx.x / NSL, sl = blockIdx.x % NSL;
    const int qi = b * 2 + d;
    const int si = b * 2 + (1 - d);
    const int tid = threadIdx.x;

    __shared__ int Pq[NREG + 1], Psx[NREG + 1];
    __shared__ float4 sp[SMAX];

    if (tid < 64) {
        const int lane = tid & 63;
        int vq = (lane < NREG) ? (int)bcnt[qi * NREG + lane] : 0;
        int vs = (lane < NREG) ? (int)bcnt[si * NREG + lane] : 0;
#pragma unroll
        for (int o = 1; o < NREG; o <<= 1) {
            int tq = __shfl_up(vq, o);
            int ts = __shfl_up(vs, o);
            if (lane >= o) { vq += tq; vs += ts; }
        }
        if (lane < NREG) { Pq[lane + 1] = vq; Psx[lane + 1] = vs; }
        if (lane == 0) { Pq[0] = 0; Psx[0] = 0; }
    }
    __syncthreads();

    const int nq = Pq[NREG], ns = Psx[NREG];
    if (qc * QPB >= nq) return;                    // block-uniform exit
    const int L = (ns + NSL - 1) / NSL;
    const int start = sl * L;
    int len = ns - start; if (len > L) len = L;
    if (len <= 0) return;                          // block-uniform exit

    if (tid < len) {                               // L <= 256 = BLK
        const int id = start + tid;
        const int r = map_region(Psx, id);
        sp[tid] = pts[(size_t)si * CAP + r * BLK + (id - Psx[r])];
    }
    __syncthreads();

    float qx[QPT], qy[QPT], qz[QPT], bt[QPT];
    bool qv[QPT]; int qn[QPT];
#pragma unroll
    for (int k = 0; k < QPT; ++k) {
        const int q = qc * QPB + k * BLK + tid;
        qn[k] = q; qv[k] = q < nq;
        const int qq = qv[k] ? q : 0;
        const int r = map_region(Pq, qq);
        const float4 p = pts[(size_t)qi * CAP + r * BLK + (qq - Pq[r])];
        qx[k] = 0.5f * p.x; qy[k] = 0.5f * p.y; qz[k] = 0.5f * p.z;
        bt[k] = -1e30f;
    }

#pragma unroll 4
    for (int j = 0; j < len; ++j) {
        const float4 s = sp[j];                    // wave-uniform -> broadcast
#pragma unroll
        for (int k = 0; k < QPT; ++k) {
            float t = fmaf(qx[k], s.x, s.w);
            t = fmaf(qy[k], s.y, t);
            t = fmaf(qz[k], s.z, t);
            bt[k] = fmaxf(bt[k], t);
        }
    }

#pragma unroll
    for (int k = 0; k < QPT; ++k)
        if (qv[k])
            atomicMax(&best[(size_t)qi * CAP + qn[k]], enc_f(bt[k]));
}

// ---------------------------------------------------------------------------
// One block per (b,side,chunk): decode best for dense q, threshold, partials.
// Writes psum/pcnt unconditionally (zeros for empty chunks) - no init needed.
// ---------------------------------------------------------------------------
__global__ __launch_bounds__(BLK) void finalize_kernel(
    const unsigned* __restrict__ bcnt, const float4* __restrict__ pts,
    const unsigned* __restrict__ best, float* __restrict__ psum,
    float* __restrict__ pcnt)
{
    const int b = blockIdx.z, side = blockIdx.y, bx = blockIdx.x;
    const int qi = b * 2 + side;
    const int tid = threadIdx.x;

    __shared__ int Pq[NREG + 1];
    build_prefix(bcnt, qi, Pq, tid);
    __syncthreads();

    const int nq = Pq[NREG];
    const int q = bx * BLK + tid;
    float s = 0.f, c = 0.f;
    if (q < nq) {
        const int r = map_region(Pq, q);
        const float4 p = pts[(size_t)qi * CAP + r * BLK + (q - Pq[r])];
        const float t = dec_f(best[(size_t)qi * CAP + q]);
        float dd = fmaxf((-p.w) - t, 0.f);
        if (dd < THR) { s = dd; c = 1.f; }
    }
#pragma unroll
    for (int off = 32; off; off >>= 1) {
        s += __shfl_down(s, off);
        c += __shfl_down(c, off);
    }
    __shared__ float red[8];
    const int w = tid >> 6;
    if ((tid & 63) == 0) { red[w] = s; red[4 + w] = c; }
    __syncthreads();
    if (tid == 0) {
        psum[qi * NREG + bx] = red[0] + red[1] + red[2] + red[3];
        pcnt[qi * NREG + bx] = red[4] + red[5] + red[6] + red[7];
    }
}

// Sum 256 partials -> scalar. 1 block, 64 threads; lanes 0..7 own one qi each.
__global__ void reduce_out_kernel(const float* __restrict__ psum,
                                  const float* __restrict__ pcnt,
                                  float* __restrict__ out)
{
    const int tid = threadIdx.x;
    float a = 0.f;
    if (tid < 8) {
        float s = 0.f, c = 0.f;
        for (int r = 0; r < NREG; ++r) {
            s += psum[tid * NREG + r];
            c += pcnt[tid * NREG + r];
        }
        a = s / c;
    }
#pragma unroll
    for (int off = 4; off; off >>= 1) a += __shfl_down(a, off);
    if (tid == 0) out[0] = a;
}

extern "C" void kernel_launch(void* const* d_in, const int* in_sizes, int n_in,
                              void* d_out, int out_size, void* d_ws, size_t ws_size,
                              hipStream_t stream)
{
    const float* Ps = (const float*)d_in[0];   // points_src  [B,N,3]
    const float* Pd = (const float*)d_in[1];   // points_dst  [B,N,3]
    const float* F  = (const float*)d_in[2];   // flows_pred  [B,N,3]
    // d_in[3] = flows_gt (unused by reference)
    const int* Ms = (const int*)d_in[4];       // masks_src [B,N]
    const int* Md = (const int*)d_in[5];       // masks_dst [B,N]
    float* out = (float*)d_out;

    unsigned* bcnt = (unsigned*)d_ws;
    float* psum = (float*)((char*)d_ws + OFF_PSUM);
    float* pcnt = (float*)((char*)d_ws + OFF_PCNT);
    unsigned* best = (unsigned*)((char*)d_ws + OFF_BEST);
    float4* pts = (float4*)((char*)d_ws + OFF_PTS);

    compact_kernel<<<dim3(NREG, 2, NB), BLK, 0, stream>>>(
        Ps, Pd, F, Ms, Md, bcnt, pts, best);

    knn_kernel<<<dim3(NQC_MAX * NSL, 2, NB), BLK, 0, stream>>>(bcnt, pts, best);

    finalize_kernel<<<dim3(NREG, 2, NB), BLK, 0, stream>>>(
        bcnt, pts, best, psum, pcnt);

    reduce_out_kernel<<<1, 64, 0, stream>>>(psum, pcnt, out);
}

// Round 6
// 30.642 us; speedup vs baseline: 2.4105x; 1.1086x over previous
//
#include <hip/hip_runtime.h>
#include <hip/hip_bf16.h>

#define NPTS 8192
#define NB   4
#define BLK  256
#define RAWC 1024                 // raw queries per chunk
#define NQC  (NPTS / RAWC)        // 8 chunks
#define NSL  16                   // search slices
#define SRAW (NPTS / NSL)         // 512 raw search points per slice
#define THR  3.33f

// workspace (word offsets into ctl = (unsigned*)d_ws):
//   ctl[qi*32]        per-qi done counters (qi<8, 128B apart)
//   ctl[256]          global done2 counter
//   ctl[288..296)     mean[8] (f32)
//   ctl[1024..1088)   psum[64] (f32)   written unconditionally
//   ctl[1152..1216)   pcnt[64] (f32)   written unconditionally
//   byte 16384 ...    part[8][NSL][NPTS] f32 = 4 MB, valid dense slots only
#define OFF_PART 16384

__device__ __forceinline__ void load_pt(int side, int g,
    const float* __restrict__ Ps, const float* __restrict__ Pd,
    const float* __restrict__ F,  const int* __restrict__ Ms,
    const int* __restrict__ Md,
    float& x, float& y, float& z, bool& v)
{
    if (side == 0) {               // warped src
        x = Ps[3*g+0] + F[3*g+0];
        y = Ps[3*g+1] + F[3*g+1];
        z = Ps[3*g+2] + F[3*g+2];
        v = Ms[g] > 0;
    } else {                       // dst
        x = Pd[3*g+0]; y = Pd[3*g+1]; z = Pd[3*g+2];
        v = Md[g] > 0;
    }
}

// dense inner loop, KMAX dense queries per thread (static regs, rule #20)
template<int KMAX>
__device__ __forceinline__ void inner_loop(const float4* __restrict__ sp, int sd,
                                           const float4* __restrict__ qb, int nd,
                                           float* __restrict__ pb, int tid)
{
    float qx[KMAX], qy[KMAX], qz[KMAX], bt[KMAX];
#pragma unroll
    for (int k = 0; k < KMAX; ++k) {
        const int q = k * BLK + tid;
        const float4 p = qb[q < nd ? q : 0];
        qx[k] = p.x; qy[k] = p.y; qz[k] = p.z;
        bt[k] = -1e30f;
    }
#pragma unroll 4
    for (int j = 0; j < sd; ++j) {
        const float4 s = sp[j];            // wave-uniform -> LDS broadcast
#pragma unroll
        for (int k = 0; k < KMAX; ++k) {
            float t = fmaf(qx[k], s.x, s.w);
            t = fmaf(qy[k], s.y, t);
            t = fmaf(qz[k], s.z, t);
            bt[k] = fmaxf(bt[k], t);
        }
    }
#pragma unroll
    for (int k = 0; k < KMAX; ++k) {
        const int q = k * BLK + tid;
        if (q < nd) pb[q] = bt[k];         // coalesced plain store
    }
}

// ---------------------------------------------------------------------------
// knn: block = (chunk qc, slice sl, dir, b). Compacts its own raw query chunk
// and search slice into LDS, runs the dense max-t loop, stores per-slice
// partial maxima to part. Block (0,0,0) also zeroes the ticket words.
// ---------------------------------------------------------------------------
__global__ __launch_bounds__(BLK) void knn_kernel(
    const float* __restrict__ Ps, const float* __restrict__ Pd,
    const float* __restrict__ F,  const int* __restrict__ Ms,
    const int* __restrict__ Md,   float* __restrict__ part,
    unsigned* __restrict__ ctl)
{
    const int b = blockIdx.z, dir = blockIdx.y;
    const int qc = blockIdx.x / NSL, sl = blockIdx.x % NSL;
    const int tid = threadIdx.x, lane = tid & 63, w = tid >> 6;
    const int qi = b * 2 + dir;

    if (blockIdx.x == 0 && dir == 0 && b == 0)
        for (int i = tid; i < 512; i += BLK) ctl[i] = 0;   // tickets+mean

    __shared__ float4 qb[RAWC];
    __shared__ float4 sp[SRAW];
    __shared__ int wcq[4], wcs[4], cnt_s[2];

    // raw loads: 4 query pts + 2 search pts per thread
    float qxr[4], qyr[4], qzr[4]; bool qvr[4];
#pragma unroll
    for (int r = 0; r < 4; ++r) {
        const int g = b * NPTS + qc * RAWC + r * BLK + tid;
        load_pt(dir, g, Ps, Pd, F, Ms, Md, qxr[r], qyr[r], qzr[r], qvr[r]);
    }
    float sxr[2], syr[2], szr[2]; bool svr[2];
#pragma unroll
    for (int r = 0; r < 2; ++r) {
        const int g = b * NPTS + sl * SRAW + r * BLK + tid;
        load_pt(1 - dir, g, Ps, Pd, F, Ms, Md, sxr[r], syr[r], szr[r], svr[r]);
    }

    // block-wide stable compaction (wave scan + cross-wave offsets)
    const int cq = (int)qvr[0] + qvr[1] + qvr[2] + qvr[3];
    const int cs = (int)svr[0] + svr[1];
    int pq = cq, ps = cs;
#pragma unroll
    for (int o = 1; o < 64; o <<= 1) {
        int t1 = __shfl_up(pq, o), t2 = __shfl_up(ps, o);
        if (lane >= o) { pq += t1; ps += t2; }
    }
    if (lane == 63) { wcq[w] = pq; wcs[w] = ps; }
    __syncthreads();
    int bq = 0, bs = 0;
#pragma unroll
    for (int i = 0; i < 4; ++i) if (i < w) { bq += wcq[i]; bs += wcs[i]; }
    int oq = bq + pq - cq;
    int os = bs + ps - cs;
#pragma unroll
    for (int r = 0; r < 4; ++r)
        if (qvr[r]) { qb[oq] = make_float4(qxr[r], qyr[r], qzr[r], 0.f); ++oq; }
#pragma unroll
    for (int r = 0; r < 2; ++r)
        if (svr[r]) {
            sp[os] = make_float4(2.f * sxr[r], 2.f * syr[r], 2.f * szr[r],
                                 -(sxr[r]*sxr[r] + syr[r]*syr[r] + szr[r]*szr[r]));
            ++os;
        }
    if (tid == BLK - 1) { cnt_s[0] = bq + pq; cnt_s[1] = bs + ps; }
    __syncthreads();
    const int nd = cnt_s[0], sd = cnt_s[1];

    float* pb = part + ((size_t)qi * NSL + sl) * NPTS + qc * RAWC;
    switch ((nd + BLK - 1) >> 8) {         // block-uniform KMAX dispatch
        case 1: inner_loop<1>(sp, sd, qb, nd, pb, tid); break;
        case 2: inner_loop<2>(sp, sd, qb, nd, pb, tid); break;
        case 3: inner_loop<3>(sp, sd, qb, nd, pb, tid); break;
        case 4: inner_loop<4>(sp, sd, qb, nd, pb, tid); break;
        default: break;                    // nd == 0
    }
}

// ---------------------------------------------------------------------------
// final: block = (qc, dir, b). Re-runs the identical compaction scan (same
// dense order as knn), reduces max over NSL slice partials, thresholds,
// block-reduces, then 2-level ticket (8-per-qi, then 8 qi) writes out[0].
// ---------------------------------------------------------------------------
__global__ __launch_bounds__(BLK) void final_kernel(
    const float* __restrict__ Ps, const float* __restrict__ Pd,
    const float* __restrict__ F,  const int* __restrict__ Ms,
    const int* __restrict__ Md,   const float* __restrict__ part,
    unsigned* __restrict__ ctl,   float* __restrict__ out)
{
    const int b = blockIdx.z, dir = blockIdx.y, qc = blockIdx.x;
    const int tid = threadIdx.x, lane = tid & 63, w = tid >> 6;
    const int qi = b * 2 + dir;

    __shared__ float q2b[RAWC];
    __shared__ int wcq[4], nd_s;

    float qxr[4], qyr[4], qzr[4]; bool qvr[4];
#pragma unroll
    for (int r = 0; r < 4; ++r) {
        const int g = b * NPTS + qc * RAWC + r * BLK + tid;
        load_pt(dir, g, Ps, Pd, F, Ms, Md, qxr[r], qyr[r], qzr[r], qvr[r]);
    }
    const int cq = (int)qvr[0] + qvr[1] + qvr[2] + qvr[3];
    int pq = cq;
#pragma unroll
    for (int o = 1; o < 64; o <<= 1) {
        int t1 = __shfl_up(pq, o);
        if (lane >= o) pq += t1;
    }
    if (lane == 63) wcq[w] = pq;
    __syncthreads();
    int bq = 0;
#pragma unroll
    for (int i = 0; i < 4; ++i) if (i < w) bq += wcq[i];
    int oq = bq + pq - cq;
#pragma unroll
    for (int r = 0; r < 4; ++r)
        if (qvr[r]) {
            q2b[oq] = fmaf(qxr[r], qxr[r], fmaf(qyr[r], qyr[r], qzr[r] * qzr[r]));
            ++oq;
        }
    if (tid == BLK - 1) nd_s = bq + pq;
    __syncthreads();
    const int nd = nd_s;

    const float* pp = part + (size_t)qi * NSL * NPTS + qc * RAWC;
    float s = 0.f, c = 0.f;
    for (int dq = tid; dq < nd; dq += BLK) {
        float m = -1e30f;
#pragma unroll
        for (int sl = 0; sl < NSL; ++sl)
            m = fmaxf(m, pp[(size_t)sl * NPTS + dq]);   // coalesced
        const float dd = fmaxf(q2b[dq] - m, 0.f);
        if (dd < THR) { s += dd; c += 1.f; }
    }
#pragma unroll
    for (int off = 32; off; off >>= 1) {
        s += __shfl_down(s, off);
        c += __shfl_down(c, off);
    }
    __shared__ float red[8];
    if (lane == 0) { red[w] = s; red[4 + w] = c; }
    __syncthreads();
    if (tid == 0) {
        float* psum  = (float*)(ctl + 1024);
        float* pcnt  = (float*)(ctl + 1152);
        float* meanv = (float*)(ctl + 288);
        psum[qi * NQC + qc] = red[0] + red[1] + red[2] + red[3];
        pcnt[qi * NQC + qc] = red[4] + red[5] + red[6] + red[7];
        const unsigned r = __hip_atomic_fetch_add(&ctl[qi * 32], 1u,
                              __ATOMIC_ACQ_REL, __HIP_MEMORY_SCOPE_AGENT);
        if (r == NQC - 1) {                 // last block of this qi
            float S = 0.f, C = 0.f;
            for (int g = 0; g < NQC; ++g) {
                S += psum[qi * NQC + g];
                C += pcnt[qi * NQC + g];
            }
            meanv[qi] = S / C;
            const unsigned r2 = __hip_atomic_fetch_add(&ctl[256], 1u,
                                   __ATOMIC_ACQ_REL, __HIP_MEMORY_SCOPE_AGENT);
            if (r2 == 2 * NB - 1) {         // very last qi
                float a = 0.f;
#pragma unroll
                for (int i = 0; i < 2 * NB; ++i) a += meanv[i];
                out[0] = a;
            }
        }
    }
}

extern "C" void kernel_launch(void* const* d_in, const int* in_sizes, int n_in,
                              void* d_out, int out_size, void* d_ws, size_t ws_size,
                              hipStream_t stream)
{
    const float* Ps = (const float*)d_in[0];   // points_src  [B,N,3]
    const float* Pd = (const float*)d_in[1];   // points_dst  [B,N,3]
    const float* F  = (const float*)d_in[2];   // flows_pred  [B,N,3]
    // d_in[3] = flows_gt (unused by reference)
    const int* Ms = (const int*)d_in[4];       // masks_src [B,N]
    const int* Md = (const int*)d_in[5];       // masks_dst [B,N]
    float* out = (float*)d_out;

    unsigned* ctl = (unsigned*)d_ws;
    float* part = (float*)((char*)d_ws + OFF_PART);

    knn_kernel<<<dim3(NQC * NSL, 2, NB), BLK, 0, stream>>>(
        Ps, Pd, F, Ms, Md, part, ctl);

    final_kernel<<<dim3(NQC, 2, NB), BLK, 0, stream>>>(
        Ps, Pd, F, Ms, Md, part, ctl, out);
}